// Round 2
// baseline (118.724 us; speedup 1.0000x reference)
//
#include <hip/hip_runtime.h>

// RelativePositionEncoding: out[i,j,c] = W[dres][c] + W[65+dtok][c]
//                                      + same_entity*W[130][c] + W[131+dch][c]
// B=1, N=1024, CZ=128, W: [136][128] fp32. Output 512 MiB fp32 — HBM-write-bound.
// Roofline: fillBuffer on this chip = 6.7 TB/s write -> ~80 us for 536.9 MB.
//
// This version: 1024-thread blocks (LDS 73.7KB -> 2 blocks/CU = 32 waves/CU,
// 100% occupancy), i-side scalars packed into one uint32 each and staged in
// LDS (broadcast ds_read_b32 + readfirstlane -> scalar unpack; removes 5
// global loads per iteration), nontemporal streaming stores.

typedef float f4 __attribute__((ext_vector_type(4)));

constexpr int ROWS = 136;          // 65 rel_pos | 65 rel_token | 1 entity | 5 rel_chain
constexpr int THREADS = 1024;
constexpr int GRID = 512;          // 524,288 threads; each stores 64 float4

__global__ __launch_bounds__(THREADS)
void relpos_kernel(const int* __restrict__ asym,
                   const int* __restrict__ resid,
                   const int* __restrict__ ent,
                   const int* __restrict__ tok,
                   const int* __restrict__ sym,
                   const float* __restrict__ W,
                   f4* __restrict__ outv)
{
    __shared__ f4 sW[ROWS * 32];        // 69,632 B
    __shared__ uint32_t sPk[1024 + 16]; // packed i-side scalars, padded for prefetch
    const int tid = threadIdx.x;

    // ---- stage W (coalesced float4) + pack the 5 int arrays ----
    const f4* Wv = reinterpret_cast<const f4*>(W);
    for (int k = tid; k < ROWS * 32; k += THREADS)
        sW[k] = Wv[k];
    {
        // asym 0..7 (3b) | resid 0..1023 (10b) | ent 0..3 (2b) | tok 0..1023 (10b) | sym 0..3 (2b)
        const uint32_t pk = (uint32_t)asym[tid]
                          | ((uint32_t)resid[tid] << 3)
                          | ((uint32_t)ent[tid]   << 13)
                          | ((uint32_t)tok[tid]   << 15)
                          | ((uint32_t)sym[tid]   << 25);
        sPk[tid] = pk;
        if (tid < 16) sPk[1024 + tid] = 0u;   // prefetch pad
    }
    __syncthreads();

    // ---- decomposition: t -> (c4 = channel float4, j fixed, i block-uniform) ----
    const int t  = blockIdx.x * THREADS + tid;
    const int c4 = t & 31;
    const int p0 = t >> 5;
    const int j  = p0 & 1023;     // 32 consecutive j per block
    int i        = p0 >> 10;      // = blockIdx/32, block-uniform, in [0,16)

    const uint32_t pkj = sPk[j];
    const int aj  = pkj & 7;
    const int rj  = (pkj >> 3)  & 1023;
    const int ej  = (pkj >> 13) & 3;
    const int tj  = (pkj >> 15) & 1023;
    const int sj  = (pkj >> 25) & 3;
    const int rjb = rj + 32, tjb = tj + 32, sjb = sj + 2;

    const f4 vE = sW[130 * 32 + c4];    // entity row hoisted

    size_t oidx = (size_t)t;
    uint32_t pk = sPk[i];
    #pragma unroll 4
    for (int it = 0; it < 64; ++it) {
        const uint32_t pkc = (uint32_t)__builtin_amdgcn_readfirstlane((int)pk);
        pk = sPk[i + 16];               // prefetch next iter (padded, safe)

        const int ai = pkc & 7;
        const int ri = (pkc >> 3)  & 1023;
        const int ei = (pkc >> 13) & 3;
        const int ti = (pkc >> 15) & 1023;
        const int si = (pkc >> 25) & 3;

        const bool sc  = (ai == aj);
        const bool scr = sc || (ri == rj);

        int dres = min(max(rjb - ri, 0), 64);
        int dtok = min(max(tjb - ti, 0), 64);
        int dch  = min(max(sjb - si, 0), 4);
        if (sc)  { dres = 64; dch = 4; }
        if (scr) { dtok = 64; }
        const float se = (ei == ej) ? 1.0f : 0.0f;

        const f4 v0 = sW[dres * 32 + c4];
        const f4 v1 = sW[(65 + dtok) * 32 + c4];
        const f4 v3 = sW[(131 + dch) * 32 + c4];

        // reference fp32 order: ((t0 + t1) + se*w130) + t3
        f4 r;
        r.x = fmaf(se, vE.x, v0.x + v1.x) + v3.x;
        r.y = fmaf(se, vE.y, v0.y + v1.y) + v3.y;
        r.z = fmaf(se, vE.z, v0.z + v1.z) + v3.z;
        r.w = fmaf(se, vE.w, v0.w + v1.w) + v3.w;

        __builtin_nontemporal_store(r, &outv[oidx]);
        oidx += (size_t)GRID * THREADS;
        i += 16;
    }
}

extern "C" void kernel_launch(void* const* d_in, const int* in_sizes, int n_in,
                              void* d_out, int out_size, void* d_ws, size_t ws_size,
                              hipStream_t stream) {
    const int*   asym  = (const int*)  d_in[0];
    const int*   resid = (const int*)  d_in[1];
    const int*   ent   = (const int*)  d_in[2];
    const int*   tok   = (const int*)  d_in[3];
    const int*   sym   = (const int*)  d_in[4];
    const float* W     = (const float*)d_in[5];
    f4* outv = (f4*)d_out;

    relpos_kernel<<<GRID, THREADS, 0, stream>>>(asym, resid, ent, tok, sym, W, outv);
}

// Round 3
// 117.438 us; speedup vs baseline: 1.0109x; 1.0109x over previous
//
#include <hip/hip_runtime.h>

// RelativePositionEncoding: out[i,j,c] = W[dres][c] + W[65+dtok][c]
//                                      + same_entity*W[130][c] + W[131+dch][c]
// B=1, N=1024, CZ=128, W: [136][128] fp32. Output 512 MiB fp32 — HBM-write-bound.
// Roofline: fillBuffer on this chip = 6.7 TB/s write -> ~80 us for 536.9 MB.
//
// R3 theory: R1/R2 stuck at 4.5 TB/s because each wave had ~1 outstanding store
// (store gated by ds_read+lgkmcnt chain). Little's law: 16 waves/CU x 1KB /
// ~900ns = 4.6 TB/s = measured. Fix: batch 8 results in registers, then 8
// back-to-back stores -> ~8KB in flight per wave. Plain stores (no nt).

typedef float f4 __attribute__((ext_vector_type(4)));

constexpr int ROWS = 136;          // 65 rel_pos | 65 rel_token | 1 entity | 5 rel_chain
constexpr int THREADS = 512;
constexpr int GRID = 1024;         // 524,288 threads; each stores 64 float4
constexpr int BATCH = 8;

__global__ __launch_bounds__(THREADS)
void relpos_kernel(const int* __restrict__ asym,
                   const int* __restrict__ resid,
                   const int* __restrict__ ent,
                   const int* __restrict__ tok,
                   const int* __restrict__ sym,
                   const float* __restrict__ W,
                   f4* __restrict__ outv)
{
    __shared__ f4 sW[ROWS * 32];     // 69,632 B
    __shared__ uint32_t sPk[1024];   // packed scalars: 4 KB  (total 73.7 KB -> 2 blocks/CU)
    const int tid = threadIdx.x;

    // ---- stage W (coalesced float4) + pack the 5 int arrays ----
    const f4* Wv = reinterpret_cast<const f4*>(W);
    for (int k = tid; k < ROWS * 32; k += THREADS)
        sW[k] = Wv[k];
    for (int k = tid; k < 1024; k += THREADS) {
        // asym 3b | resid 10b | ent 2b | tok 10b | sym 2b
        sPk[k] = (uint32_t)asym[k]
               | ((uint32_t)resid[k] << 3)
               | ((uint32_t)ent[k]   << 13)
               | ((uint32_t)tok[k]   << 15)
               | ((uint32_t)sym[k]   << 25);
    }
    __syncthreads();

    // ---- decomposition: t -> (c4, j fixed per thread, i0 block-uniform) ----
    const int t  = blockIdx.x * THREADS + tid;
    const int c4 = t & 31;
    const int p0 = t >> 5;
    const int j  = p0 & 1023;     // 16 consecutive j per block
    const int i0 = p0 >> 10;      // block-uniform, in [0,16); i = i0 + 16*it

    const uint32_t pkj = sPk[j];
    const int aj  = pkj & 7;
    const int rjb = ((pkj >> 3)  & 1023) + 32;
    const int ej  = (pkj >> 13) & 3;
    const int tjb = ((pkj >> 15) & 1023) + 32;
    const int sjb = ((pkj >> 25) & 3) + 2;
    const int rj  = rjb - 32;

    const f4 vE = sW[130 * 32 + c4];    // entity row hoisted

    size_t oidx = (size_t)t;
    for (int b8 = 0; b8 < 64 / BATCH; ++b8) {
        f4 r[BATCH];
        #pragma unroll
        for (int u = 0; u < BATCH; ++u) {
            const int i = i0 + 16 * (b8 * BATCH + u);
            // i is block-uniform -> wave-uniform: broadcast read + readfirstlane
            const uint32_t pkc =
                (uint32_t)__builtin_amdgcn_readfirstlane((int)sPk[i]);

            const int ai = pkc & 7;
            const int ri = (pkc >> 3)  & 1023;
            const int ei = (pkc >> 13) & 3;
            const int ti = (pkc >> 15) & 1023;
            const int si = (pkc >> 25) & 3;

            const bool sc  = (ai == aj);
            const bool scr = sc || (ri == rj);

            int dres = min(max(rjb - ri, 0), 64);
            int dtok = min(max(tjb - ti, 0), 64);
            int dch  = min(max(sjb - si, 0), 4);
            if (sc)  { dres = 64; dch = 4; }
            if (scr) { dtok = 64; }
            const float se = (ei == ej) ? 1.0f : 0.0f;

            const f4 v0 = sW[dres * 32 + c4];
            const f4 v1 = sW[(65 + dtok) * 32 + c4];
            const f4 v3 = sW[(131 + dch) * 32 + c4];

            // reference fp32 order: ((t0 + t1) + se*w130) + t3
            r[u].x = fmaf(se, vE.x, v0.x + v1.x) + v3.x;
            r[u].y = fmaf(se, vE.y, v0.y + v1.y) + v3.y;
            r[u].z = fmaf(se, vE.z, v0.z + v1.z) + v3.z;
            r[u].w = fmaf(se, vE.w, v0.w + v1.w) + v3.w;
        }
        // back-to-back stores: ~8 KB in flight per wave
        #pragma unroll
        for (int u = 0; u < BATCH; ++u) {
            outv[oidx] = r[u];
            oidx += (size_t)GRID * THREADS;   // 524,288 float4 = 8 MiB
        }
    }
}

extern "C" void kernel_launch(void* const* d_in, const int* in_sizes, int n_in,
                              void* d_out, int out_size, void* d_ws, size_t ws_size,
                              hipStream_t stream) {
    const int*   asym  = (const int*)  d_in[0];
    const int*   resid = (const int*)  d_in[1];
    const int*   ent   = (const int*)  d_in[2];
    const int*   tok   = (const int*)  d_in[3];
    const int*   sym   = (const int*)  d_in[4];
    const float* W     = (const float*)d_in[5];
    f4* outv = (f4*)d_out;

    relpos_kernel<<<GRID, THREADS, 0, stream>>>(asym, resid, ent, tok, sym, W, outv);
}